// Round 13
// baseline (321.593 us; speedup 1.0000x reference)
//
#include <hip/hip_runtime.h>
#include <hip/hip_fp16.h>

#define N_NODES 50000
#define N_EDGES 800000
#define HID 128
#define N_CLS 40
#define CAP 64                 // bucket capacity; P(Poisson(16) >= 64) ~ 1e-19
#define TILES32 1563           // ceil(50000/32)
#define CNT_BLOCKS 3125        // 800000/256
#define DEG_SCALE 2097152.0f   // 2^21 fixed-point for ew
#define DEG_MASK ((1ull << 44) - 1)

static inline int cdiv(int a, int b) { return (a + b - 1) / b; }

// dinv from packed word: deg = low 44 bits (2^21 fixed point), +1 self loop
__device__ __forceinline__ float pdinv(unsigned long long p) {
    return rsqrtf((float)(p & DEG_MASK) * (1.0f / DEG_SCALE) + 1.0f);
}
__device__ __forceinline__ int pcnt(unsigned long long p) {
    return (int)(p >> 44);
}

// ---- bucket fill: ONE 64-bit atomic per edge gives slot index AND accumulates deg ----
__device__ __forceinline__ void fill_body(int e, const int* __restrict__ row,
                                          const int* __restrict__ col,
                                          const float* __restrict__ ew,
                                          unsigned long long* __restrict__ packed,
                                          uint2* __restrict__ bkt) {
    if (e < N_EDGES) {
        int c = col[e];
        float w = ew[e];
        unsigned long long v =
            (1ull << 44) | (unsigned long long)__float2uint_rn(w * DEG_SCALE);
        unsigned long long old = atomicAdd(&packed[c], v);
        int pos = pcnt(old);
        if (pos < CAP)
            bkt[(size_t)c * CAP + pos] = make_uint2((unsigned)row[e], __float_as_uint(w));
    }
}

// ---- gemm128 body: R10-proven — function-local __shared__, BK=32, fp16 out ----
__device__ __forceinline__ void gemm128_body(int b, const float* __restrict__ X,
                                             const float* __restrict__ W,
                                             __half* __restrict__ out) {
    __shared__ float xsT[128][36];
    __shared__ float wch[32][128];
    const int t = threadIdx.x;
    const int row0 = b * 32;

    #pragma unroll
    for (int i = 0; i < 4; ++i) {
        int idx = t + i * 256;
        int row = idx >> 5;
        int k4  = idx & 31;
        float4 v = make_float4(0.f, 0.f, 0.f, 0.f);
        if (row0 + row < N_NODES)
            v = *(const float4*)&X[(size_t)(row0 + row) * 128 + k4 * 4];
        xsT[k4 * 4 + 0][row] = v.x;
        xsT[k4 * 4 + 1][row] = v.y;
        xsT[k4 * 4 + 2][row] = v.z;
        xsT[k4 * 4 + 3][row] = v.w;
    }

    const int c0 = (t & 31) * 4;
    const int r0 = (t >> 5) * 4;
    float acc[4][4];
    #pragma unroll
    for (int i = 0; i < 4; ++i)
        #pragma unroll
        for (int j = 0; j < 4; ++j) acc[i][j] = 0.f;

    for (int kk = 0; kk < 128; kk += 32) {
        __syncthreads();
        #pragma unroll
        for (int i = 0; i < 4; ++i) {
            int idx = t + i * 256;
            int wr = idx >> 5;
            int wc4 = idx & 31;
            *(float4*)&wch[wr][wc4 * 4] =
                *(const float4*)&W[(size_t)(kk + wr) * 128 + wc4 * 4];
        }
        __syncthreads();
        #pragma unroll 4
        for (int k = 0; k < 32; ++k) {
            float4 a = *(const float4*)&xsT[kk + k][r0];
            float4 w = *(const float4*)&wch[k][c0];
            acc[0][0] = fmaf(a.x, w.x, acc[0][0]);
            acc[0][1] = fmaf(a.x, w.y, acc[0][1]);
            acc[0][2] = fmaf(a.x, w.z, acc[0][2]);
            acc[0][3] = fmaf(a.x, w.w, acc[0][3]);
            acc[1][0] = fmaf(a.y, w.x, acc[1][0]);
            acc[1][1] = fmaf(a.y, w.y, acc[1][1]);
            acc[1][2] = fmaf(a.y, w.z, acc[1][2]);
            acc[1][3] = fmaf(a.y, w.w, acc[1][3]);
            acc[2][0] = fmaf(a.z, w.x, acc[2][0]);
            acc[2][1] = fmaf(a.z, w.y, acc[2][1]);
            acc[2][2] = fmaf(a.z, w.z, acc[2][2]);
            acc[2][3] = fmaf(a.z, w.w, acc[2][3]);
            acc[3][0] = fmaf(a.w, w.x, acc[3][0]);
            acc[3][1] = fmaf(a.w, w.y, acc[3][1]);
            acc[3][2] = fmaf(a.w, w.z, acc[3][2]);
            acc[3][3] = fmaf(a.w, w.w, acc[3][3]);
        }
    }

    #pragma unroll
    for (int i = 0; i < 4; ++i) {
        int r = row0 + r0 + i;
        if (r < N_NODES) {
            union { __half2 h2[2]; float2 f2; } u;
            u.h2[0] = __floats2half2_rn(acc[i][0], acc[i][1]);
            u.h2[1] = __floats2half2_rn(acc[i][2], acc[i][3]);
            *(float2*)&out[(size_t)r * 128 + c0] = u.f2;
        }
    }
}

// fat dispatch: odd blocks bucket-fill, even blocks layer-1 gemm
__global__ __launch_bounds__(256) void fused_gemm1_fill(
    const float* __restrict__ X, const float* __restrict__ W, __half* __restrict__ out,
    const int* __restrict__ row, const int* __restrict__ col,
    const float* __restrict__ ew, unsigned long long* __restrict__ packed,
    uint2* __restrict__ bkt) {
    int id = blockIdx.x;
    if (id & 1) {
        fill_body((id >> 1) * 256 + threadIdx.x, row, col, ew, packed, bkt);
    } else {
        int b = id >> 1;
        if (b < TILES32) gemm128_body(b, X, W, out);
    }
}

__device__ __forceinline__ void fma_h8(float w, uint4 g, float* acc) {
    float2 a0 = __half22float2(*(const __half2*)&g.x);
    float2 a1 = __half22float2(*(const __half2*)&g.y);
    float2 a2 = __half22float2(*(const __half2*)&g.z);
    float2 a3 = __half22float2(*(const __half2*)&g.w);
    acc[0] = fmaf(w, a0.x, acc[0]);
    acc[1] = fmaf(w, a0.y, acc[1]);
    acc[2] = fmaf(w, a1.x, acc[2]);
    acc[3] = fmaf(w, a1.y, acc[3]);
    acc[4] = fmaf(w, a2.x, acc[4]);
    acc[5] = fmaf(w, a2.y, acc[5]);
    acc[6] = fmaf(w, a3.x, acc[6]);
    acc[7] = fmaf(w, a3.y, acc[7]);
}

// agg for one node, 16-lane quarter-wave, 8 feats/lane (uint4 gathers).
// On-the-fly norm from packed deg: w = pdinv(packed[src])*ew*dn.
__device__ __forceinline__ void agg128_node16(int node, int sl,
                                              const unsigned long long* __restrict__ packed,
                                              const uint2* __restrict__ bkt,
                                              const __half* __restrict__ h,
                                              const float* __restrict__ bias,
                                              float* acc) {
    #pragma unroll
    for (int j = 0; j < 8; ++j) acc[j] = 0.f;
    if (node >= N_NODES) return;
    int f = sl * 8;
    unsigned long long pn = packed[node];
    float dn = pdinv(pn);
    int beg = node * CAP;
    int end = beg + min(pcnt(pn), CAP);
    int k = beg;
    for (; k + 8 <= end; k += 8) {
        uint2 e0 = bkt[k],   e1 = bkt[k+1], e2 = bkt[k+2], e3 = bkt[k+3];
        uint2 e4 = bkt[k+4], e5 = bkt[k+5], e6 = bkt[k+6], e7 = bkt[k+7];
        uint4 g0 = *(const uint4*)&h[(size_t)e0.x * 128 + f];
        uint4 g1 = *(const uint4*)&h[(size_t)e1.x * 128 + f];
        uint4 g2 = *(const uint4*)&h[(size_t)e2.x * 128 + f];
        uint4 g3 = *(const uint4*)&h[(size_t)e3.x * 128 + f];
        uint4 g4 = *(const uint4*)&h[(size_t)e4.x * 128 + f];
        uint4 g5 = *(const uint4*)&h[(size_t)e5.x * 128 + f];
        uint4 g6 = *(const uint4*)&h[(size_t)e6.x * 128 + f];
        uint4 g7 = *(const uint4*)&h[(size_t)e7.x * 128 + f];
        float w0 = pdinv(packed[e0.x]) * __uint_as_float(e0.y) * dn;
        float w1 = pdinv(packed[e1.x]) * __uint_as_float(e1.y) * dn;
        float w2 = pdinv(packed[e2.x]) * __uint_as_float(e2.y) * dn;
        float w3 = pdinv(packed[e3.x]) * __uint_as_float(e3.y) * dn;
        float w4 = pdinv(packed[e4.x]) * __uint_as_float(e4.y) * dn;
        float w5 = pdinv(packed[e5.x]) * __uint_as_float(e5.y) * dn;
        float w6 = pdinv(packed[e6.x]) * __uint_as_float(e6.y) * dn;
        float w7 = pdinv(packed[e7.x]) * __uint_as_float(e7.y) * dn;
        fma_h8(w0, g0, acc);
        fma_h8(w1, g1, acc);
        fma_h8(w2, g2, acc);
        fma_h8(w3, g3, acc);
        fma_h8(w4, g4, acc);
        fma_h8(w5, g5, acc);
        fma_h8(w6, g6, acc);
        fma_h8(w7, g7, acc);
    }
    for (; k + 4 <= end; k += 4) {
        uint2 e0 = bkt[k], e1 = bkt[k+1], e2 = bkt[k+2], e3 = bkt[k+3];
        uint4 g0 = *(const uint4*)&h[(size_t)e0.x * 128 + f];
        uint4 g1 = *(const uint4*)&h[(size_t)e1.x * 128 + f];
        uint4 g2 = *(const uint4*)&h[(size_t)e2.x * 128 + f];
        uint4 g3 = *(const uint4*)&h[(size_t)e3.x * 128 + f];
        float w0 = pdinv(packed[e0.x]) * __uint_as_float(e0.y) * dn;
        float w1 = pdinv(packed[e1.x]) * __uint_as_float(e1.y) * dn;
        float w2 = pdinv(packed[e2.x]) * __uint_as_float(e2.y) * dn;
        float w3 = pdinv(packed[e3.x]) * __uint_as_float(e3.y) * dn;
        fma_h8(w0, g0, acc);
        fma_h8(w1, g1, acc);
        fma_h8(w2, g2, acc);
        fma_h8(w3, g3, acc);
    }
    for (; k < end; ++k) {
        uint2 e = bkt[k];
        uint4 g = *(const uint4*)&h[(size_t)e.x * 128 + f];
        float w = pdinv(packed[e.x]) * __uint_as_float(e.y) * dn;
        fma_h8(w, g, acc);
    }
    // self loop + bias + relu
    uint4 gs = *(const uint4*)&h[(size_t)node * 128 + f];
    fma_h8(dn * dn, gs, acc);
    float4 b0 = *(const float4*)&bias[f];
    float4 b1 = *(const float4*)&bias[f + 4];
    acc[0] = fmaxf(acc[0] + b0.x, 0.f);
    acc[1] = fmaxf(acc[1] + b0.y, 0.f);
    acc[2] = fmaxf(acc[2] + b0.z, 0.f);
    acc[3] = fmaxf(acc[3] + b0.w, 0.f);
    acc[4] = fmaxf(acc[4] + b1.x, 0.f);
    acc[5] = fmaxf(acc[5] + b1.y, 0.f);
    acc[6] = fmaxf(acc[6] + b1.z, 0.f);
    acc[7] = fmaxf(acc[7] + b1.w, 0.f);
}

// aggregate 32 nodes into xsT (transposed, relu+bias applied)
__device__ __forceinline__ void agg_tile_to_lds(int row0,
                                                const unsigned long long* packed,
                                                const uint2* bkt, const __half* h,
                                                const float* bias, float (*xsT)[36]) {
    int wave = threadIdx.x >> 6;
    int lane = threadIdx.x & 63;
    int sub  = lane >> 4;        // 0..3
    int sl   = lane & 15;        // 0..15
    int f = sl * 8;
    #pragma unroll
    for (int i = 0; i < 2; ++i) {
        int r = i * 16 + wave * 4 + sub;
        float acc[8];
        agg128_node16(row0 + r, sl, packed, bkt, h, bias, acc);
        #pragma unroll
        for (int j = 0; j < 8; ++j)
            xsT[f + j][r] = acc[j];
    }
}

// Fused: aggregate 32 nodes (layer L) -> LDS tile -> GEMM W(L+1), BK=16 -> fp16 out.
// LDS 26.6KB -> 6 blocks/CU (occupancy for the latency-bound gather phase).
__global__ __launch_bounds__(256) void agg_gemm128_kernel(
    const unsigned long long* __restrict__ packed, const uint2* __restrict__ bkt,
    const __half* __restrict__ h, const float* __restrict__ bias,
    const float* __restrict__ W, __half* __restrict__ out) {
    __shared__ float xsT[128][36];
    __shared__ float wch[16][128];
    const int t = threadIdx.x;
    const int row0 = blockIdx.x * 32;

    agg_tile_to_lds(row0, packed, bkt, h, bias, xsT);

    const int c0 = (t & 31) * 4;
    const int r0 = (t >> 5) * 4;
    float acc[4][4];
    #pragma unroll
    for (int i = 0; i < 4; ++i)
        #pragma unroll
        for (int j = 0; j < 4; ++j) acc[i][j] = 0.f;

    for (int kk = 0; kk < 128; kk += 16) {
        __syncthreads();   // first iteration: protects xsT written by agg phase
        #pragma unroll
        for (int i = 0; i < 2; ++i) {
            int idx = t + i * 256;       // [0,512)
            int wr = idx >> 5;           // 0..15
            int wc4 = idx & 31;
            *(float4*)&wch[wr][wc4 * 4] =
                *(const float4*)&W[(size_t)(kk + wr) * 128 + wc4 * 4];
        }
        __syncthreads();
        #pragma unroll 4
        for (int k = 0; k < 16; ++k) {
            float4 a = *(const float4*)&xsT[kk + k][r0];
            float4 w = *(const float4*)&wch[k][c0];
            acc[0][0] = fmaf(a.x, w.x, acc[0][0]);
            acc[0][1] = fmaf(a.x, w.y, acc[0][1]);
            acc[0][2] = fmaf(a.x, w.z, acc[0][2]);
            acc[0][3] = fmaf(a.x, w.w, acc[0][3]);
            acc[1][0] = fmaf(a.y, w.x, acc[1][0]);
            acc[1][1] = fmaf(a.y, w.y, acc[1][1]);
            acc[1][2] = fmaf(a.y, w.z, acc[1][2]);
            acc[1][3] = fmaf(a.y, w.w, acc[1][3]);
            acc[2][0] = fmaf(a.z, w.x, acc[2][0]);
            acc[2][1] = fmaf(a.z, w.y, acc[2][1]);
            acc[2][2] = fmaf(a.z, w.z, acc[2][2]);
            acc[2][3] = fmaf(a.z, w.w, acc[2][3]);
            acc[3][0] = fmaf(a.w, w.x, acc[3][0]);
            acc[3][1] = fmaf(a.w, w.y, acc[3][1]);
            acc[3][2] = fmaf(a.w, w.z, acc[3][2]);
            acc[3][3] = fmaf(a.w, w.w, acc[3][3]);
        }
    }

    #pragma unroll
    for (int i = 0; i < 4; ++i) {
        int r = row0 + r0 + i;
        if (r < N_NODES) {
            union { __half2 h2[2]; float2 f2; } u;
            u.h2[0] = __floats2half2_rn(acc[i][0], acc[i][1]);
            u.h2[1] = __floats2half2_rn(acc[i][2], acc[i][3]);
            *(float2*)&out[(size_t)r * 128 + c0] = u.f2;
        }
    }
}

// Fused: aggregate 32 nodes -> LDS tile -> 128x40 GEMM W3 -> fp16 out [N,64-stride]
__global__ __launch_bounds__(256) void agg_gemm40_kernel(
    const unsigned long long* __restrict__ packed, const uint2* __restrict__ bkt,
    const __half* __restrict__ h, const float* __restrict__ bias,
    const float* __restrict__ W3, __half* __restrict__ out) {
    __shared__ float xsT[128][36];
    const int row0 = blockIdx.x * 32;
    agg_tile_to_lds(row0, packed, bkt, h, bias, xsT);
    __syncthreads();
    for (int idx = threadIdx.x; idx < 32 * N_CLS; idx += 256) {
        int r = idx / N_CLS;
        int c = idx % N_CLS;
        float acc = 0.f;
        #pragma unroll 8
        for (int k = 0; k < 128; ++k)
            acc = fmaf(xsT[k][r], W3[k * N_CLS + c], acc);
        int node = row0 + r;
        if (node < N_NODES)
            out[(size_t)node * 64 + c] = __float2half(acc);   // stride 64, line-aligned
    }
}

// Final aggregation, F=40 (stride-64 fp16 table), on-the-fly norm, fp32 out.
__global__ __launch_bounds__(256) void agg40_kernel(
    const unsigned long long* __restrict__ packed, const uint2* __restrict__ bkt,
    const __half* __restrict__ h, const float* __restrict__ b,
    float* __restrict__ out) {
    int wave = threadIdx.x >> 6;
    int lane = threadIdx.x & 63;
    int node = blockIdx.x * 4 + wave;
    if (node >= N_NODES || lane >= N_CLS) return;
    unsigned long long pn = packed[node];
    float dn = pdinv(pn);
    int beg = node * CAP;
    int end = beg + min(pcnt(pn), CAP);
    float acc = 0.f;
    int k = beg;
    for (; k + 4 <= end; k += 4) {
        uint2 e0 = bkt[k], e1 = bkt[k+1], e2 = bkt[k+2], e3 = bkt[k+3];
        float g0 = __half2float(h[(size_t)e0.x * 64 + lane]);
        float g1 = __half2float(h[(size_t)e1.x * 64 + lane]);
        float g2 = __half2float(h[(size_t)e2.x * 64 + lane]);
        float g3 = __half2float(h[(size_t)e3.x * 64 + lane]);
        float w0 = pdinv(packed[e0.x]) * __uint_as_float(e0.y) * dn;
        float w1 = pdinv(packed[e1.x]) * __uint_as_float(e1.y) * dn;
        float w2 = pdinv(packed[e2.x]) * __uint_as_float(e2.y) * dn;
        float w3 = pdinv(packed[e3.x]) * __uint_as_float(e3.y) * dn;
        acc = fmaf(w0, g0, acc);
        acc = fmaf(w1, g1, acc);
        acc = fmaf(w2, g2, acc);
        acc = fmaf(w3, g3, acc);
    }
    for (; k < end; ++k) {
        uint2 e = bkt[k];
        float w = pdinv(packed[e.x]) * __uint_as_float(e.y) * dn;
        acc = fmaf(w, __half2float(h[(size_t)e.x * 64 + lane]), acc);
    }
    acc = fmaf(dn * dn, __half2float(h[(size_t)node * 64 + lane]), acc) + b[lane];
    out[(size_t)node * N_CLS + lane] = acc;
}

extern "C" void kernel_launch(void* const* d_in, const int* in_sizes, int n_in,
                              void* d_out, int out_size, void* d_ws, size_t ws_size,
                              hipStream_t stream) {
    const float* x  = (const float*)d_in[0];
    const float* ew = (const float*)d_in[1];
    const float* W1 = (const float*)d_in[2];
    const float* b1 = (const float*)d_in[3];
    const float* W2 = (const float*)d_in[4];
    const float* b2 = (const float*)d_in[5];
    const float* W3 = (const float*)d_in[6];
    const float* b3 = (const float*)d_in[7];
    const int*   ei = (const int*)d_in[8];
    const int* row = ei;
    const int* col = ei + N_EDGES;
    float* out = (float*)d_out;

    char* ws = (char*)d_ws;
    size_t off = 0;
    auto alloc = [&](size_t bytes) -> void* {
        void* p = (void*)(ws + off);
        off = (off + bytes + 255) & ~(size_t)255;
        return p;
    };
    unsigned long long* packed = (unsigned long long*)alloc((size_t)N_NODES * 8);
    uint2*  bkt  = (uint2*)alloc((size_t)N_NODES * CAP * 8);   // 25.6 MB
    __half* h16a = (__half*)alloc((size_t)N_NODES * HID * 2);
    __half* h16b = (__half*)alloc((size_t)N_NODES * HID * 2);
    __half* h40  = (__half*)alloc((size_t)N_NODES * 64 * 2);   // stride 64

    hipMemsetAsync(packed, 0, (size_t)N_NODES * 8, stream);

    // D1: bucket fill (one packed atomic: slot cursor + deg) || layer-1 gemm -> h16a
    fused_gemm1_fill<<<2 * CNT_BLOCKS, 256, 0, stream>>>(x, W1, h16a, row, col, ew,
                                                         packed, bkt);
    // D2: agg layer1 (h16a, on-the-fly dinv) + gemm W2 (BK=16) -> h16b
    agg_gemm128_kernel<<<TILES32, 256, 0, stream>>>(packed, bkt, h16a, b1, W2, h16b);
    // D3: agg layer2 (h16b) + gemm W3 -> h40 (stride 64)
    agg_gemm40_kernel<<<TILES32, 256, 0, stream>>>(packed, bkt, h16b, b2, W3, h40);
    // D4: final aggregation -> out
    agg40_kernel<<<cdiv(N_NODES, 4), 256, 0, stream>>>(packed, bkt, h40, b3, out);
}

// Round 14
// 299.689 us; speedup vs baseline: 1.0731x; 1.0731x over previous
//
#include <hip/hip_runtime.h>
#include <hip/hip_fp16.h>

#define N_NODES 50000
#define N_EDGES 800000
#define HID 128
#define N_CLS 40
#define CAP 64                 // bucket capacity; P(Poisson(16) >= 64) ~ 1e-19
#define TILES32 1563           // ceil(50000/32)
#define CNT_BLOCKS 3125        // 800000/256
#define DINV_BLOCKS 196        // ceil(50000/256)
#define DEG_SCALE 2097152.0f   // 2^21 fixed-point for ew
#define DEG_MASK ((1ull << 44) - 1)

static inline int cdiv(int a, int b) { return (a + b - 1) / b; }

__device__ __forceinline__ int pcnt(unsigned long long p) {
    return (int)(p >> 44);
}

// ---- bucket fill: ONE 64-bit atomic per edge gives slot index AND accumulates deg ----
__device__ __forceinline__ void fill_body(int e, const int* __restrict__ row,
                                          const int* __restrict__ col,
                                          const float* __restrict__ ew,
                                          unsigned long long* __restrict__ packed,
                                          uint2* __restrict__ bkt) {
    if (e < N_EDGES) {
        int c = col[e];
        float w = ew[e];
        unsigned long long v =
            (1ull << 44) | (unsigned long long)__float2uint_rn(w * DEG_SCALE);
        unsigned long long old = atomicAdd(&packed[c], v);
        int pos = pcnt(old);
        if (pos < CAP)
            bkt[(size_t)c * CAP + pos] = make_uint2((unsigned)row[e], __float_as_uint(w));
    }
}

// ---- gemm128 body: R10-proven — function-local __shared__, BK=32, fp16 out ----
__device__ __forceinline__ void gemm128_body(int b, const float* __restrict__ X,
                                             const float* __restrict__ W,
                                             __half* __restrict__ out) {
    __shared__ float xsT[128][36];
    __shared__ float wch[32][128];
    const int t = threadIdx.x;
    const int row0 = b * 32;

    #pragma unroll
    for (int i = 0; i < 4; ++i) {
        int idx = t + i * 256;
        int row = idx >> 5;
        int k4  = idx & 31;
        float4 v = make_float4(0.f, 0.f, 0.f, 0.f);
        if (row0 + row < N_NODES)
            v = *(const float4*)&X[(size_t)(row0 + row) * 128 + k4 * 4];
        xsT[k4 * 4 + 0][row] = v.x;
        xsT[k4 * 4 + 1][row] = v.y;
        xsT[k4 * 4 + 2][row] = v.z;
        xsT[k4 * 4 + 3][row] = v.w;
    }

    const int c0 = (t & 31) * 4;
    const int r0 = (t >> 5) * 4;
    float acc[4][4];
    #pragma unroll
    for (int i = 0; i < 4; ++i)
        #pragma unroll
        for (int j = 0; j < 4; ++j) acc[i][j] = 0.f;

    for (int kk = 0; kk < 128; kk += 32) {
        __syncthreads();
        #pragma unroll
        for (int i = 0; i < 4; ++i) {
            int idx = t + i * 256;
            int wr = idx >> 5;
            int wc4 = idx & 31;
            *(float4*)&wch[wr][wc4 * 4] =
                *(const float4*)&W[(size_t)(kk + wr) * 128 + wc4 * 4];
        }
        __syncthreads();
        #pragma unroll 4
        for (int k = 0; k < 32; ++k) {
            float4 a = *(const float4*)&xsT[kk + k][r0];
            float4 w = *(const float4*)&wch[k][c0];
            acc[0][0] = fmaf(a.x, w.x, acc[0][0]);
            acc[0][1] = fmaf(a.x, w.y, acc[0][1]);
            acc[0][2] = fmaf(a.x, w.z, acc[0][2]);
            acc[0][3] = fmaf(a.x, w.w, acc[0][3]);
            acc[1][0] = fmaf(a.y, w.x, acc[1][0]);
            acc[1][1] = fmaf(a.y, w.y, acc[1][1]);
            acc[1][2] = fmaf(a.y, w.z, acc[1][2]);
            acc[1][3] = fmaf(a.y, w.w, acc[1][3]);
            acc[2][0] = fmaf(a.z, w.x, acc[2][0]);
            acc[2][1] = fmaf(a.z, w.y, acc[2][1]);
            acc[2][2] = fmaf(a.z, w.z, acc[2][2]);
            acc[2][3] = fmaf(a.z, w.w, acc[2][3]);
            acc[3][0] = fmaf(a.w, w.x, acc[3][0]);
            acc[3][1] = fmaf(a.w, w.y, acc[3][1]);
            acc[3][2] = fmaf(a.w, w.z, acc[3][2]);
            acc[3][3] = fmaf(a.w, w.w, acc[3][3]);
        }
    }

    #pragma unroll
    for (int i = 0; i < 4; ++i) {
        int r = row0 + r0 + i;
        if (r < N_NODES) {
            union { __half2 h2[2]; float2 f2; } u;
            u.h2[0] = __floats2half2_rn(acc[i][0], acc[i][1]);
            u.h2[1] = __floats2half2_rn(acc[i][2], acc[i][3]);
            *(float2*)&out[(size_t)r * 128 + c0] = u.f2;
        }
    }
}

// fat dispatch: odd blocks bucket-fill, even blocks layer-1 gemm
__global__ __launch_bounds__(256) void fused_gemm1_fill(
    const float* __restrict__ X, const float* __restrict__ W, __half* __restrict__ out,
    const int* __restrict__ row, const int* __restrict__ col,
    const float* __restrict__ ew, unsigned long long* __restrict__ packed,
    uint2* __restrict__ bkt) {
    int id = blockIdx.x;
    if (id & 1) {
        fill_body((id >> 1) * 256 + threadIdx.x, row, col, ew, packed, bkt);
    } else {
        int b = id >> 1;
        if (b < TILES32) gemm128_body(b, X, W, out);
    }
}

// tiny elementwise: dinv[i] = rsqrt(deg_i + 1) from packed low bits (~3 us)
__global__ __launch_bounds__(256) void dinv_from_packed(
    const unsigned long long* __restrict__ packed, float* __restrict__ dinv) {
    int i = blockIdx.x * 256 + threadIdx.x;
    if (i < N_NODES)
        dinv[i] = rsqrtf((float)(packed[i] & DEG_MASK) * (1.0f / DEG_SCALE) + 1.0f);
}

__device__ __forceinline__ void fma_h8(float w, uint4 g, float* acc) {
    float2 a0 = __half22float2(*(const __half2*)&g.x);
    float2 a1 = __half22float2(*(const __half2*)&g.y);
    float2 a2 = __half22float2(*(const __half2*)&g.z);
    float2 a3 = __half22float2(*(const __half2*)&g.w);
    acc[0] = fmaf(w, a0.x, acc[0]);
    acc[1] = fmaf(w, a0.y, acc[1]);
    acc[2] = fmaf(w, a1.x, acc[2]);
    acc[3] = fmaf(w, a1.y, acc[3]);
    acc[4] = fmaf(w, a2.x, acc[4]);
    acc[5] = fmaf(w, a2.y, acc[5]);
    acc[6] = fmaf(w, a3.x, acc[6]);
    acc[7] = fmaf(w, a3.y, acc[7]);
}

// agg for one node, 16-lane quarter-wave, 8 feats/lane (uint4 gathers).
// On-the-fly norm via precomputed float dinv table (R12-proven): w = dinv[src]*ew*dn.
__device__ __forceinline__ void agg128_node16(int node, int sl,
                                              const unsigned long long* __restrict__ packed,
                                              const uint2* __restrict__ bkt,
                                              const __half* __restrict__ h,
                                              const float* __restrict__ dinv,
                                              const float* __restrict__ bias,
                                              float* acc) {
    #pragma unroll
    for (int j = 0; j < 8; ++j) acc[j] = 0.f;
    if (node >= N_NODES) return;
    int f = sl * 8;
    float dn = dinv[node];
    int beg = node * CAP;
    int end = beg + min(pcnt(packed[node]), CAP);
    int k = beg;
    for (; k + 8 <= end; k += 8) {
        uint2 e0 = bkt[k],   e1 = bkt[k+1], e2 = bkt[k+2], e3 = bkt[k+3];
        uint2 e4 = bkt[k+4], e5 = bkt[k+5], e6 = bkt[k+6], e7 = bkt[k+7];
        uint4 g0 = *(const uint4*)&h[(size_t)e0.x * 128 + f];
        uint4 g1 = *(const uint4*)&h[(size_t)e1.x * 128 + f];
        uint4 g2 = *(const uint4*)&h[(size_t)e2.x * 128 + f];
        uint4 g3 = *(const uint4*)&h[(size_t)e3.x * 128 + f];
        uint4 g4 = *(const uint4*)&h[(size_t)e4.x * 128 + f];
        uint4 g5 = *(const uint4*)&h[(size_t)e5.x * 128 + f];
        uint4 g6 = *(const uint4*)&h[(size_t)e6.x * 128 + f];
        uint4 g7 = *(const uint4*)&h[(size_t)e7.x * 128 + f];
        float w0 = dinv[e0.x] * __uint_as_float(e0.y) * dn;
        float w1 = dinv[e1.x] * __uint_as_float(e1.y) * dn;
        float w2 = dinv[e2.x] * __uint_as_float(e2.y) * dn;
        float w3 = dinv[e3.x] * __uint_as_float(e3.y) * dn;
        float w4 = dinv[e4.x] * __uint_as_float(e4.y) * dn;
        float w5 = dinv[e5.x] * __uint_as_float(e5.y) * dn;
        float w6 = dinv[e6.x] * __uint_as_float(e6.y) * dn;
        float w7 = dinv[e7.x] * __uint_as_float(e7.y) * dn;
        fma_h8(w0, g0, acc);
        fma_h8(w1, g1, acc);
        fma_h8(w2, g2, acc);
        fma_h8(w3, g3, acc);
        fma_h8(w4, g4, acc);
        fma_h8(w5, g5, acc);
        fma_h8(w6, g6, acc);
        fma_h8(w7, g7, acc);
    }
    for (; k + 4 <= end; k += 4) {
        uint2 e0 = bkt[k], e1 = bkt[k+1], e2 = bkt[k+2], e3 = bkt[k+3];
        uint4 g0 = *(const uint4*)&h[(size_t)e0.x * 128 + f];
        uint4 g1 = *(const uint4*)&h[(size_t)e1.x * 128 + f];
        uint4 g2 = *(const uint4*)&h[(size_t)e2.x * 128 + f];
        uint4 g3 = *(const uint4*)&h[(size_t)e3.x * 128 + f];
        float w0 = dinv[e0.x] * __uint_as_float(e0.y) * dn;
        float w1 = dinv[e1.x] * __uint_as_float(e1.y) * dn;
        float w2 = dinv[e2.x] * __uint_as_float(e2.y) * dn;
        float w3 = dinv[e3.x] * __uint_as_float(e3.y) * dn;
        fma_h8(w0, g0, acc);
        fma_h8(w1, g1, acc);
        fma_h8(w2, g2, acc);
        fma_h8(w3, g3, acc);
    }
    for (; k < end; ++k) {
        uint2 e = bkt[k];
        uint4 g = *(const uint4*)&h[(size_t)e.x * 128 + f];
        float w = dinv[e.x] * __uint_as_float(e.y) * dn;
        fma_h8(w, g, acc);
    }
    // self loop + bias + relu
    uint4 gs = *(const uint4*)&h[(size_t)node * 128 + f];
    fma_h8(dn * dn, gs, acc);
    float4 b0 = *(const float4*)&bias[f];
    float4 b1 = *(const float4*)&bias[f + 4];
    acc[0] = fmaxf(acc[0] + b0.x, 0.f);
    acc[1] = fmaxf(acc[1] + b0.y, 0.f);
    acc[2] = fmaxf(acc[2] + b0.z, 0.f);
    acc[3] = fmaxf(acc[3] + b0.w, 0.f);
    acc[4] = fmaxf(acc[4] + b1.x, 0.f);
    acc[5] = fmaxf(acc[5] + b1.y, 0.f);
    acc[6] = fmaxf(acc[6] + b1.z, 0.f);
    acc[7] = fmaxf(acc[7] + b1.w, 0.f);
}

// aggregate 32 nodes into xsT (transposed, relu+bias applied)
__device__ __forceinline__ void agg_tile_to_lds(int row0,
                                                const unsigned long long* packed,
                                                const uint2* bkt, const __half* h,
                                                const float* dinv, const float* bias,
                                                float (*xsT)[36]) {
    int wave = threadIdx.x >> 6;
    int lane = threadIdx.x & 63;
    int sub  = lane >> 4;        // 0..3
    int sl   = lane & 15;        // 0..15
    int f = sl * 8;
    #pragma unroll
    for (int i = 0; i < 2; ++i) {
        int r = i * 16 + wave * 4 + sub;
        float acc[8];
        agg128_node16(row0 + r, sl, packed, bkt, h, dinv, bias, acc);
        #pragma unroll
        for (int j = 0; j < 8; ++j)
            xsT[f + j][r] = acc[j];
    }
}

// Fused: aggregate 32 nodes (layer L) -> LDS tile -> GEMM W(L+1), BK=16 -> fp16 out.
__global__ __launch_bounds__(256) void agg_gemm128_kernel(
    const unsigned long long* __restrict__ packed, const uint2* __restrict__ bkt,
    const __half* __restrict__ h, const float* __restrict__ dinv,
    const float* __restrict__ bias, const float* __restrict__ W,
    __half* __restrict__ out) {
    __shared__ float xsT[128][36];
    __shared__ float wch[16][128];
    const int t = threadIdx.x;
    const int row0 = blockIdx.x * 32;

    agg_tile_to_lds(row0, packed, bkt, h, dinv, bias, xsT);

    const int c0 = (t & 31) * 4;
    const int r0 = (t >> 5) * 4;
    float acc[4][4];
    #pragma unroll
    for (int i = 0; i < 4; ++i)
        #pragma unroll
        for (int j = 0; j < 4; ++j) acc[i][j] = 0.f;

    for (int kk = 0; kk < 128; kk += 16) {
        __syncthreads();   // first iteration: protects xsT written by agg phase
        #pragma unroll
        for (int i = 0; i < 2; ++i) {
            int idx = t + i * 256;       // [0,512)
            int wr = idx >> 5;           // 0..15
            int wc4 = idx & 31;
            *(float4*)&wch[wr][wc4 * 4] =
                *(const float4*)&W[(size_t)(kk + wr) * 128 + wc4 * 4];
        }
        __syncthreads();
        #pragma unroll 4
        for (int k = 0; k < 16; ++k) {
            float4 a = *(const float4*)&xsT[kk + k][r0];
            float4 w = *(const float4*)&wch[k][c0];
            acc[0][0] = fmaf(a.x, w.x, acc[0][0]);
            acc[0][1] = fmaf(a.x, w.y, acc[0][1]);
            acc[0][2] = fmaf(a.x, w.z, acc[0][2]);
            acc[0][3] = fmaf(a.x, w.w, acc[0][3]);
            acc[1][0] = fmaf(a.y, w.x, acc[1][0]);
            acc[1][1] = fmaf(a.y, w.y, acc[1][1]);
            acc[1][2] = fmaf(a.y, w.z, acc[1][2]);
            acc[1][3] = fmaf(a.y, w.w, acc[1][3]);
            acc[2][0] = fmaf(a.z, w.x, acc[2][0]);
            acc[2][1] = fmaf(a.z, w.y, acc[2][1]);
            acc[2][2] = fmaf(a.z, w.z, acc[2][2]);
            acc[2][3] = fmaf(a.z, w.w, acc[2][3]);
            acc[3][0] = fmaf(a.w, w.x, acc[3][0]);
            acc[3][1] = fmaf(a.w, w.y, acc[3][1]);
            acc[3][2] = fmaf(a.w, w.z, acc[3][2]);
            acc[3][3] = fmaf(a.w, w.w, acc[3][3]);
        }
    }

    #pragma unroll
    for (int i = 0; i < 4; ++i) {
        int r = row0 + r0 + i;
        if (r < N_NODES) {
            union { __half2 h2[2]; float2 f2; } u;
            u.h2[0] = __floats2half2_rn(acc[i][0], acc[i][1]);
            u.h2[1] = __floats2half2_rn(acc[i][2], acc[i][3]);
            *(float2*)&out[(size_t)r * 128 + c0] = u.f2;
        }
    }
}

// Fused: aggregate 32 nodes -> LDS tile -> 128x40 GEMM W3 -> fp16 out [N,64-stride]
__global__ __launch_bounds__(256) void agg_gemm40_kernel(
    const unsigned long long* __restrict__ packed, const uint2* __restrict__ bkt,
    const __half* __restrict__ h, const float* __restrict__ dinv,
    const float* __restrict__ bias, const float* __restrict__ W3,
    __half* __restrict__ out) {
    __shared__ float xsT[128][36];
    const int row0 = blockIdx.x * 32;
    agg_tile_to_lds(row0, packed, bkt, h, dinv, bias, xsT);
    __syncthreads();
    for (int idx = threadIdx.x; idx < 32 * N_CLS; idx += 256) {
        int r = idx / N_CLS;
        int c = idx % N_CLS;
        float acc = 0.f;
        #pragma unroll 8
        for (int k = 0; k < 128; ++k)
            acc = fmaf(xsT[k][r], W3[k * N_CLS + c], acc);
        int node = row0 + r;
        if (node < N_NODES)
            out[(size_t)node * 64 + c] = __float2half(acc);   // stride 64, line-aligned
    }
}

// Final aggregation, F=40 (stride-64 fp16 table), dinv-table norm, fp32 out.
__global__ __launch_bounds__(256) void agg40_kernel(
    const unsigned long long* __restrict__ packed, const uint2* __restrict__ bkt,
    const __half* __restrict__ h, const float* __restrict__ dinv,
    const float* __restrict__ b, float* __restrict__ out) {
    int wave = threadIdx.x >> 6;
    int lane = threadIdx.x & 63;
    int node = blockIdx.x * 4 + wave;
    if (node >= N_NODES || lane >= N_CLS) return;
    float dn = dinv[node];
    int beg = node * CAP;
    int end = beg + min(pcnt(packed[node]), CAP);
    float acc = 0.f;
    int k = beg;
    for (; k + 4 <= end; k += 4) {
        uint2 e0 = bkt[k], e1 = bkt[k+1], e2 = bkt[k+2], e3 = bkt[k+3];
        float g0 = __half2float(h[(size_t)e0.x * 64 + lane]);
        float g1 = __half2float(h[(size_t)e1.x * 64 + lane]);
        float g2 = __half2float(h[(size_t)e2.x * 64 + lane]);
        float g3 = __half2float(h[(size_t)e3.x * 64 + lane]);
        float w0 = dinv[e0.x] * __uint_as_float(e0.y) * dn;
        float w1 = dinv[e1.x] * __uint_as_float(e1.y) * dn;
        float w2 = dinv[e2.x] * __uint_as_float(e2.y) * dn;
        float w3 = dinv[e3.x] * __uint_as_float(e3.y) * dn;
        acc = fmaf(w0, g0, acc);
        acc = fmaf(w1, g1, acc);
        acc = fmaf(w2, g2, acc);
        acc = fmaf(w3, g3, acc);
    }
    for (; k < end; ++k) {
        uint2 e = bkt[k];
        float w = dinv[e.x] * __uint_as_float(e.y) * dn;
        acc = fmaf(w, __half2float(h[(size_t)e.x * 64 + lane]), acc);
    }
    acc = fmaf(dn * dn, __half2float(h[(size_t)node * 64 + lane]), acc) + b[lane];
    out[(size_t)node * N_CLS + lane] = acc;
}

extern "C" void kernel_launch(void* const* d_in, const int* in_sizes, int n_in,
                              void* d_out, int out_size, void* d_ws, size_t ws_size,
                              hipStream_t stream) {
    const float* x  = (const float*)d_in[0];
    const float* ew = (const float*)d_in[1];
    const float* W1 = (const float*)d_in[2];
    const float* b1 = (const float*)d_in[3];
    const float* W2 = (const float*)d_in[4];
    const float* b2 = (const float*)d_in[5];
    const float* W3 = (const float*)d_in[6];
    const float* b3 = (const float*)d_in[7];
    const int*   ei = (const int*)d_in[8];
    const int* row = ei;
    const int* col = ei + N_EDGES;
    float* out = (float*)d_out;

    char* ws = (char*)d_ws;
    size_t off = 0;
    auto alloc = [&](size_t bytes) -> void* {
        void* p = (void*)(ws + off);
        off = (off + bytes + 255) & ~(size_t)255;
        return p;
    };
    unsigned long long* packed = (unsigned long long*)alloc((size_t)N_NODES * 8);
    float*  dinv = (float*)alloc((size_t)N_NODES * 4);
    uint2*  bkt  = (uint2*)alloc((size_t)N_NODES * CAP * 8);   // 25.6 MB
    __half* h16a = (__half*)alloc((size_t)N_NODES * HID * 2);
    __half* h16b = (__half*)alloc((size_t)N_NODES * HID * 2);
    __half* h40  = (__half*)alloc((size_t)N_NODES * 64 * 2);   // stride 64

    hipMemsetAsync(packed, 0, (size_t)N_NODES * 8, stream);

    // D1: bucket fill (one packed atomic: slot cursor + deg) || layer-1 gemm -> h16a
    fused_gemm1_fill<<<2 * CNT_BLOCKS, 256, 0, stream>>>(x, W1, h16a, row, col, ew,
                                                         packed, bkt);
    // D2: tiny elementwise dinv reconstruction (~3 us)
    dinv_from_packed<<<DINV_BLOCKS, 256, 0, stream>>>(packed, dinv);
    // D3: agg layer1 (h16a, dinv table) + gemm W2 (BK=16) -> h16b
    agg_gemm128_kernel<<<TILES32, 256, 0, stream>>>(packed, bkt, h16a, dinv, b1, W2, h16b);
    // D4: agg layer2 (h16b) + gemm W3 -> h40 (stride 64)
    agg_gemm40_kernel<<<TILES32, 256, 0, stream>>>(packed, bkt, h16b, dinv, b2, W3, h40);
    // D5: final aggregation -> out
    agg40_kernel<<<cdiv(N_NODES, 4), 256, 0, stream>>>(packed, bkt, h40, dinv, b3, out);
}